// Round 15
// baseline (241.671 us; speedup 1.0000x reference)
//
#include <hip/hip_runtime.h>
#include <math.h>

// GCN 2-layer forward on MI355X — round 15:
//  * rank array eliminated: count pass atomics are fire-and-forget (no return
//    dependency -> no vmcnt stall under gemm1); scan1 converts counts_rep
//    in place into per-(node,rep) cursors; fill claims slots directly with
//    one returning atomic per edge.
//  * otherwise r14 structure (h~ pre-scaling, pp_s top-scan, W2 hi-only)
#define CH   128
#define CH4  32
#define TPB  256
#define SCANB 1024
#define WIMG 16384       // shorts per (layer,colh) fragment image (32 KB)
#define NREP 8

typedef __attribute__((ext_vector_type(8))) short short8;   // 8 bf16 (4 VGPRs)
typedef __attribute__((ext_vector_type(4))) float floatx4;  // MFMA acc
typedef __attribute__((ext_vector_type(8))) float float8;

static __device__ __forceinline__ unsigned short f2bf(float f) {
    unsigned u = __float_as_uint(f);
    return (unsigned short)((u + 0x7fffu + ((u >> 16) & 1u)) >> 16);
}
static __device__ __forceinline__ float bf2f(unsigned short s) {
    return __uint_as_float(((unsigned)s) << 16);
}
static __device__ __forceinline__ float8 bf8_to_f8(short8 u) {
    float8 f;
    #pragma unroll
    for (int i = 0; i < 8; ++i) f[i] = bf2f((unsigned short)u[i]);
    return f;
}

// ---------------------------------------------------------------------------
// k_prep: blocks [0,nbPrep): split W1,W2 into bf16 hi/lo fragment images;
// blocks [nbPrep,..): zero counts_rep + done.
// ---------------------------------------------------------------------------
__global__ void k_prep(const float* __restrict__ W1, const float* __restrict__ W2,
                       short* __restrict__ Wsplit, float4* __restrict__ zbase,
                       int nzero4, int nbPrep) {
    int bx = blockIdx.x;
    if (bx >= nbPrep) {
        int i = (bx - nbPrep) * TPB + threadIdx.x;
        if (i < nzero4) zbase[i] = make_float4(0.f, 0.f, 0.f, 0.f);
        return;
    }
    int i = bx * TPB + threadIdx.x;   // over 2*128*128
    if (i >= 2 * CH * CH) return;
    int layer = i >> 14;
    int idx   = i & 16383;
    int k = idx >> 7, c = idx & 127;
    float w = (layer ? W2 : W1)[k * CH + c];
    unsigned short hi = f2bf(w);
    unsigned short lo = f2bf(w - bf2f(hi));
    int colh = c >> 6, nn = c & 63;
    int kt = k >> 5, q = (k & 31) >> 3, j = k & 7;
    int ns = nn >> 4, ln = q * 16 + (nn & 15);
    size_t base = (size_t)(layer * 2 + colh) * WIMG;
    size_t off  = ((size_t)(kt * 4 + ns) * 64 + ln) * 8 + j;
    Wsplit[base + off]        = (short)hi;   // hi: first 16 KB of image
    Wsplit[base + 8192 + off] = (short)lo;   // lo: second 16 KB
}

// ---------------------------------------------------------------------------
// fp32-input MFMA GEMM body (3-term Markidis split), bf16 output. (layer 1)
// A: m=lane&15, k=(lane>>4)*8+j ; B mirrored ; D: col=lane&15, row=(lane>>4)*4+reg
// ---------------------------------------------------------------------------
static __device__ __forceinline__ void gemm_body_f32(
        const float* __restrict__ X, const short* __restrict__ Wfrag,
        unsigned short* __restrict__ H, int n, int tile, int colh, int tid) {
    __shared__ __align__(16) short sW[2][4][4][64][8];   // 32 KB (hi+lo)
    {
        const float4* gsrc = (const float4*)Wfrag;
        float4* ldst = (float4*)sW;
        #pragma unroll
        for (int i = 0; i < 8; ++i)
            ldst[i * TPB + tid] = gsrc[i * TPB + tid];
    }
    __syncthreads();

    const int lane = tid & 63;
    const int wv   = tid >> 6;
    const int q    = lane >> 4;
    const int m    = lane & 15;
    const int row0 = tile * 64 + wv * 16;
    if (row0 >= n) return;

    int rrow = row0 + m;
    if (rrow > n - 1) rrow = n - 1;

    const float4* xr = (const float4*)(X + (size_t)rrow * CH);
    float4 xa[4][2];
    #pragma unroll
    for (int kt = 0; kt < 4; ++kt) {
        xa[kt][0] = xr[kt * 8 + q * 2 + 0];
        xa[kt][1] = xr[kt * 8 + q * 2 + 1];
    }

    floatx4 acc[4];
    #pragma unroll
    for (int ns = 0; ns < 4; ++ns) acc[ns] = (floatx4){0.f, 0.f, 0.f, 0.f};

    #pragma unroll
    for (int kt = 0; kt < 4; ++kt) {
        float xf[8] = { xa[kt][0].x, xa[kt][0].y, xa[kt][0].z, xa[kt][0].w,
                        xa[kt][1].x, xa[kt][1].y, xa[kt][1].z, xa[kt][1].w };
        short8 ah, al;
        #pragma unroll
        for (int j = 0; j < 8; ++j) {
            float v = xf[j];
            unsigned short h = f2bf(v);
            ah[j] = (short)h;
            al[j] = (short)f2bf(v - bf2f(h));
        }
        #pragma unroll
        for (int ns = 0; ns < 4; ++ns) {
            short8 bh = *(const short8*)&sW[0][kt][ns][lane][0];
            short8 bl = *(const short8*)&sW[1][kt][ns][lane][0];
            acc[ns] = __builtin_amdgcn_mfma_f32_16x16x32_bf16(ah, bh, acc[ns], 0, 0, 0);
            acc[ns] = __builtin_amdgcn_mfma_f32_16x16x32_bf16(al, bh, acc[ns], 0, 0, 0);
            acc[ns] = __builtin_amdgcn_mfma_f32_16x16x32_bf16(ah, bl, acc[ns], 0, 0, 0);
        }
    }

    #pragma unroll
    for (int ns = 0; ns < 4; ++ns) {
        #pragma unroll
        for (int reg = 0; reg < 4; ++reg) {
            int r = row0 + q * 4 + reg;
            if (r < n)
                H[(size_t)r * CH + colh * 64 + ns * 16 + m] = f2bf(acc[ns][reg]);
        }
    }
}

// fused: blocks [0, nbE4): per-edge replicated COUNT atomic, fire-and-forget
// (no return use -> no stall), grid-stride x4; blocks [nbE4, ...): gemm1.
__global__ __launch_bounds__(TPB, 4)
void k_gemm_count(const float* __restrict__ X, const short* __restrict__ Wsplit,
                  unsigned short* __restrict__ H, int n,
                  const int* __restrict__ dst, int* __restrict__ counts_rep,
                  int E, int nbE4, int Np) {
    int bx = blockIdx.x;
    if (bx < nbE4) {
        int stride = nbE4 * TPB;
        int e = bx * TPB + threadIdx.x;
        #pragma unroll
        for (int it = 0; it < 4; ++it, e += stride) {
            if (e < E) {
                int d = dst[e];
                if ((unsigned)d < (unsigned)n) {
                    int rep = e & (NREP - 1);
                    atomicAdd(&counts_rep[rep * Np + d], 1);   // no return use
                }
            }
        }
    } else {
        bx -= nbE4;
        int colh = bx & 1;
        gemm_body_f32(X, Wsplit + (size_t)colh * WIMG, H, n, bx >> 1, colh,
                      threadIdx.x);
    }
}

// bf16-input GEMM, W2 hi-only (16 KB LDS); output rows scaled by dinv[row].
__global__ __launch_bounds__(TPB, 4)
void k_gemm_bf(const unsigned short* __restrict__ X, const short* __restrict__ Wsplit,
               const float* __restrict__ dinv, unsigned short* __restrict__ H, int n) {
    __shared__ __align__(16) short sW[4][4][64][8];      // hi-only, 16 KB
    const int tid  = threadIdx.x;
    const int colh = (int)blockIdx.x & 1;
    const int tile = (int)blockIdx.x >> 1;
    {
        const float4* gsrc = (const float4*)(Wsplit + (size_t)colh * WIMG); // hi half
        float4* ldst = (float4*)sW;
        #pragma unroll
        for (int i = 0; i < 4; ++i)
            ldst[i * TPB + tid] = gsrc[i * TPB + tid];
    }
    __syncthreads();

    const int lane = tid & 63;
    const int wv   = tid >> 6;
    const int q    = lane >> 4;
    const int m    = lane & 15;
    const int row0 = tile * 64 + wv * 16;
    if (row0 >= n) return;

    int rrow = row0 + m;
    if (rrow > n - 1) rrow = n - 1;

    const short8* xr8 = (const short8*)(X + (size_t)rrow * CH);
    short8 a[4];
    #pragma unroll
    for (int kt = 0; kt < 4; ++kt) a[kt] = xr8[kt * 4 + q];

    floatx4 acc[4];
    #pragma unroll
    for (int ns = 0; ns < 4; ++ns) acc[ns] = (floatx4){0.f, 0.f, 0.f, 0.f};

    #pragma unroll
    for (int kt = 0; kt < 4; ++kt) {
        #pragma unroll
        for (int ns = 0; ns < 4; ++ns) {
            short8 bh = *(const short8*)&sW[kt][ns][lane][0];
            acc[ns] = __builtin_amdgcn_mfma_f32_16x16x32_bf16(a[kt], bh, acc[ns], 0, 0, 0);
        }
    }

    float dr[4];
    #pragma unroll
    for (int reg = 0; reg < 4; ++reg) {
        int r = row0 + q * 4 + reg;
        dr[reg] = (r < n) ? dinv[r] : 0.f;
    }
    #pragma unroll
    for (int ns = 0; ns < 4; ++ns) {
        #pragma unroll
        for (int reg = 0; reg < 4; ++reg) {
            int r = row0 + q * 4 + reg;
            if (r < n)
                H[(size_t)r * CH + colh * 64 + ns * 16 + m] =
                    f2bf(acc[ns][reg] * dr[reg]);
        }
    }
}

// ---------------------------------------------------------------------------
// scan1: read 8 replica counts -> counts_tot + block-local exclusive scan ->
// row_start; convert counts_rep IN PLACE into cursors (block-local base +
// replica offset). Last-finishing block top-scans partials into pp_s.
// Absolute position = cursor-claimed slot + pp_s[d >> 10].
// ---------------------------------------------------------------------------
__global__ __launch_bounds__(SCANB)
void k_scan1(int* __restrict__ counts_rep, int Np,
             int* __restrict__ counts_tot, int* __restrict__ row_start,
             int* __restrict__ partials, int* __restrict__ pp_s,
             int* __restrict__ done, int nb, int n) {
    __shared__ int s[SCANB];
    __shared__ int slast;
    int gid = blockIdx.x * SCANB + threadIdx.x;
    int c[NREP];
    int v = 0;
    #pragma unroll
    for (int r = 0; r < NREP; ++r) {
        c[r] = (gid < n) ? counts_rep[r * Np + gid] : 0;
        v += c[r];
    }
    s[threadIdx.x] = v;
    __syncthreads();
    for (int off = 1; off < SCANB; off <<= 1) {
        int t = (threadIdx.x >= off) ? s[threadIdx.x - off] : 0;
        __syncthreads();
        s[threadIdx.x] += t;
        __syncthreads();
    }
    if (gid < n) {
        int local = s[threadIdx.x] - v;         // block-local exclusive base
        row_start[gid]  = local;
        counts_tot[gid] = v;
        int pre = 0;
        #pragma unroll
        for (int r = 0; r < NREP; ++r) {
            counts_rep[r * Np + gid] = local + pre;   // cursor init
            pre += c[r];
        }
    }
    if (threadIdx.x == SCANB - 1) {
        partials[blockIdx.x] = s[SCANB - 1];
        __threadfence();
        int old = atomicAdd(done, 1);
        slast = (old == nb - 1);
    }
    __syncthreads();
    if (slast && threadIdx.x < 64) {
        int pv = (threadIdx.x < nb) ? atomicAdd(&partials[threadIdx.x], 0) : 0;
        int inc = pv;
        #pragma unroll
        for (int off = 1; off < 64; off <<= 1) {
            int t = __shfl_up(inc, off, 64);
            if ((threadIdx.x & 63) >= off) inc += t;
        }
        if (threadIdx.x < nb) pp_s[threadIdx.x] = inc - pv;
    }
}

// fill: claim slot via cursor atomic; edges hold {src, RAW ew} (read-only after)
__global__ void k_fill(const int* __restrict__ src, const int* __restrict__ dst,
                       const float* __restrict__ ew, int* __restrict__ cursors,
                       const int* __restrict__ pp_s, int2* __restrict__ edges,
                       int E, int n, int Np) {
    int e = blockIdx.x * blockDim.x + threadIdx.x;
    if (e >= E) return;
    int s = src[e], d = dst[e];
    if ((unsigned)s >= (unsigned)n || (unsigned)d >= (unsigned)n) return;
    int rep = e & (NREP - 1);
    int pos = atomicAdd(&cursors[rep * Np + d], 1) + pp_s[d >> 10];
    edges[pos] = make_int2(s, __float_as_int(ew[e]));
}

// ---------------------------------------------------------------------------
// k_deg_scale: 16 lanes/node. deg = 1 + sum(ew over bucket) via shfl-reduce;
// dinv = rsqrt(deg); then scale the node's h row in place: h~ = h * dinv.
// ---------------------------------------------------------------------------
__global__ __launch_bounds__(TPB)
void k_deg_scale(const int* __restrict__ row_start, const int* __restrict__ pp_s,
                 const int* __restrict__ counts, const int2* __restrict__ edges,
                 float* __restrict__ dinv, unsigned short* __restrict__ h, int n) {
    int t = blockIdx.x * blockDim.x + threadIdx.x;
    int node = t >> 4;
    if (node >= n) return;
    int tx = t & 15;
    int j0  = row_start[node] + pp_s[node >> 10];
    int cnt = counts[node];
    float sum = 0.f;
    for (int j = tx; j < cnt; j += 16)
        sum += __int_as_float(edges[j0 + j].y);
    #pragma unroll
    for (int off = 8; off; off >>= 1) sum += __shfl_down(sum, off, 16);
    float di = rsqrtf(1.0f + __shfl(sum, 0, 16));
    if (tx == 0) dinv[node] = di;
    short8* hp = (short8*)h + (size_t)node * 16 + tx;
    short8 v = *hp;
    short8 o;
    #pragma unroll
    for (int c = 0; c < 8; ++c)
        o[c] = (short)f2bf(bf2f((unsigned short)v[c]) * di);
    *hp = o;
}

// ---------------------------------------------------------------------------
// simplified aggregate core over pre-scaled h~ (16 lanes/node, short8 loads):
//   o = di * ( h~[node] + sum_e ew_e * h~[src_e] ) + bias
// ---------------------------------------------------------------------------
static __device__ __forceinline__ float8 agg_node8(
        const short8* __restrict__ h8, const int2* __restrict__ edges,
        float di, const float8 b, int node, int tx,
        const int* __restrict__ row_start, const int* __restrict__ pp_s,
        const int* __restrict__ counts) {
    float8 hv = bf8_to_f8(h8[(size_t)node * 16 + tx]);
    float8 acc;
    #pragma unroll
    for (int i = 0; i < 8; ++i) acc[i] = 0.f;

    int j   = row_start[node] + pp_s[node >> 10];
    int end = j + counts[node];

    for (; j + 8 <= end; j += 8) {
        int2 e[8];
        #pragma unroll
        for (int i = 0; i < 8; ++i) e[i] = edges[j + i];
        short8 g[8];
        #pragma unroll
        for (int i = 0; i < 8; ++i) g[i] = h8[(size_t)e[i].x * 16 + tx];
        #pragma unroll
        for (int i = 0; i < 8; ++i) {
            float w = __int_as_float(e[i].y);
            float8 gf = bf8_to_f8(g[i]);
            #pragma unroll
            for (int c = 0; c < 8; ++c) acc[c] += gf[c] * w;
        }
    }
    if (j + 4 <= end) {
        int2 e[4];
        #pragma unroll
        for (int i = 0; i < 4; ++i) e[i] = edges[j + i];
        short8 g[4];
        #pragma unroll
        for (int i = 0; i < 4; ++i) g[i] = h8[(size_t)e[i].x * 16 + tx];
        #pragma unroll
        for (int i = 0; i < 4; ++i) {
            float w = __int_as_float(e[i].y);
            float8 gf = bf8_to_f8(g[i]);
            #pragma unroll
            for (int c = 0; c < 8; ++c) acc[c] += gf[c] * w;
        }
        j += 4;
    }
    for (; j < end; ++j) {
        int2 e0 = edges[j];
        float w0 = __int_as_float(e0.y);
        float8 gf = bf8_to_f8(h8[(size_t)e0.x * 16 + tx]);
        #pragma unroll
        for (int c = 0; c < 8; ++c) acc[c] += gf[c] * w0;
    }

    float8 o;
    #pragma unroll
    for (int c = 0; c < 8; ++c) o[c] = di * (hv[c] + acc[c]) + b[c];
    return o;
}

// agg1: o1 = relu(agg(h~)) in bf16. 16 nodes/block of 256.
__global__ __launch_bounds__(TPB)
void k_aggregate1(const unsigned short* __restrict__ h,
                  const int* __restrict__ row_start, const int* __restrict__ pp_s,
                  const int* __restrict__ counts, const int2* __restrict__ edges,
                  const float* __restrict__ dinv, const float* __restrict__ bias,
                  unsigned short* __restrict__ out, int n) {
    int t = blockIdx.x * blockDim.x + threadIdx.x;
    int node = t >> 4;
    if (node >= n) return;
    int tx = t & 15;
    float8 b;
    #pragma unroll
    for (int c = 0; c < 8; ++c) b[c] = bias[tx * 8 + c];
    float8 o = agg_node8((const short8*)h, edges, dinv[node], b, node, tx,
                         row_start, pp_s, counts);
    short8 u;
    #pragma unroll
    for (int c = 0; c < 8; ++c) u[c] = (short)f2bf(fmaxf(o[c], 0.f));
    ((short8*)out)[(size_t)node * 16 + tx] = u;
}

// agg2: out = relu(agg(h2~)) in fp32.
__global__ __launch_bounds__(TPB)
void k_aggregate2(const unsigned short* __restrict__ h,
                  const int* __restrict__ row_start, const int* __restrict__ pp_s,
                  const int* __restrict__ counts, const int2* __restrict__ edges,
                  const float* __restrict__ dinv, const float* __restrict__ bias,
                  float* __restrict__ out, int n) {
    int t = blockIdx.x * blockDim.x + threadIdx.x;
    int node = t >> 4;
    if (node >= n) return;
    int tx = t & 15;
    float8 b;
    #pragma unroll
    for (int c = 0; c < 8; ++c) b[c] = bias[tx * 8 + c];
    float8 o = agg_node8((const short8*)h, edges, dinv[node], b, node, tx,
                         row_start, pp_s, counts);
    float4 lo = make_float4(fmaxf(o[0], 0.f), fmaxf(o[1], 0.f),
                            fmaxf(o[2], 0.f), fmaxf(o[3], 0.f));
    float4 hi = make_float4(fmaxf(o[4], 0.f), fmaxf(o[5], 0.f),
                            fmaxf(o[6], 0.f), fmaxf(o[7], 0.f));
    ((float4*)out)[(size_t)node * CH4 + tx * 2 + 0] = lo;
    ((float4*)out)[(size_t)node * CH4 + tx * 2 + 1] = hi;
}

// ---------------------------------------------------------------------------
extern "C" void kernel_launch(void* const* d_in, const int* in_sizes, int n_in,
                              void* d_out, int out_size, void* d_ws, size_t ws_size,
                              hipStream_t stream) {
    const float* x  = (const float*)d_in[0];   // [N,128]
    const int*   ei = (const int*)d_in[1];     // [2,E]
    const float* ew = (const float*)d_in[2];   // [E]
    const float* W1 = (const float*)d_in[3];
    const float* b1 = (const float*)d_in[4];
    const float* W2 = (const float*)d_in[5];
    const float* b2 = (const float*)d_in[6];
    float* out = (float*)d_out;                // [N,128]

    const int N = in_sizes[0] / CH;
    const int E = in_sizes[2];
    const int* src = ei;
    const int* dst = ei + E;

    // workspace layout (16B-aligned)
    size_t Np = ((size_t)N + 255) & ~(size_t)255;
    float* ws          = (float*)d_ws;
    float* dinv        = ws;                                // Np floats
    unsigned short* h  = (unsigned short*)(dinv + Np);      // N*CH bf16 (gemm1 out)
    unsigned short* o1 = h + (size_t)N * CH;                // N*CH bf16 (agg1 out)
    unsigned short* h2 = o1 + (size_t)N * CH;               // N*CH bf16 (gemm2 out)
    // ---- contiguous zero region ----
    int*   counts_rep  = (int*)(h2 + (size_t)N * CH);       // NREP*Np ints (-> cursors)
    int*   done        = counts_rep + NREP * Np;            // 64 ints (1 used)
    int    nzero4      = (int)((NREP * Np + 64) / 4);
    // ---- rest ----
    int*  counts_tot   = done + 64;                         // Np ints
    int*  row_start    = counts_tot + Np;                   // Np ints
    int*  partials     = row_start + Np;                    // 64 ints
    int*  pp_s         = partials + 64;                     // 64 ints
    int2* edges        = (int2*)(pp_s + 64);                // E int2
    short* Wsplit      = (short*)(edges + E);               // 4*WIMG shorts

    const int nbE    = (E + TPB - 1) / TPB;
    const int nbE4   = (E + TPB * 4 - 1) / (TPB * 4);
    const int nbAgg  = (int)(((size_t)N * 16 + TPB - 1) / TPB);
    const int nbScan = (N + SCANB - 1) / SCANB;     // 49 <= 64
    const int nbGemm2 = 2 * ((N + 63) / 64);
    const int nbPrep  = (2 * CH * CH + TPB - 1) / TPB;
    const int nbZero  = (nzero4 + TPB - 1) / TPB;

    // ---- prep: split W + zero counters (fused) ----
    k_prep      <<<nbPrep + nbZero, TPB, 0, stream>>>(W1, W2, Wsplit,
                                                      (float4*)counts_rep,
                                                      nzero4, nbPrep);
    // ---- fused: fire-and-forget count pass | gemm1 ----
    k_gemm_count<<<nbE4 + nbGemm2, TPB, 0, stream>>>(x, Wsplit, h, N, dst,
                                                     counts_rep, E, nbE4, (int)Np);
    // ---- CSR finalize: scan (counts -> cursors in place) + cursor fill ----
    k_scan1     <<<nbScan, SCANB, 0, stream>>>(counts_rep, (int)Np, counts_tot,
                                               row_start, partials, pp_s, done,
                                               nbScan, N);
    k_fill      <<<nbE, TPB, 0, stream>>>(src, dst, ew, counts_rep, pp_s,
                                          edges, E, N, (int)Np);
    // ---- dinv + in-place scale h -> h~ ----
    k_deg_scale <<<nbAgg, TPB, 0, stream>>>(row_start, pp_s, counts_tot, edges,
                                            dinv, h, N);
    // ---- layer 1 aggregate -> o1 (bf16, ReLU) ----
    k_aggregate1<<<nbAgg, TPB, 0, stream>>>(h, row_start, pp_s, counts_tot,
                                            edges, dinv, b1, o1, N);
    // ---- layer 2: gemm (rows pre-scaled by dinv) + aggregate ----
    k_gemm_bf   <<<nbGemm2, TPB, 0, stream>>>(o1, Wsplit + 2 * (size_t)WIMG,
                                              dinv, h2, N);
    k_aggregate2<<<nbAgg, TPB, 0, stream>>>(h2, row_start, pp_s, counts_tot,
                                            edges, dinv, b2, out, N);
}